// Round 5
// baseline (414.391 us; speedup 1.0000x reference)
//
#include <hip/hip_runtime.h>
#include <hip/hip_bf16.h>

#define N_NODES  100000
#define N_EDGES  1600000
#define N_GRAPHS 256
#define DCH      128
#define DOUT     64
#define NB       391      // buckets = ceil(100000/256)
#define PADB     512
#define SLACK    4608     // per-bucket region capacity (mean 4096 + 8 sigma)
#define CHUNK    2048     // edges per binA block

typedef short v8s __attribute__((ext_vector_type(8)));
typedef float v4f __attribute__((ext_vector_type(4)));

static __device__ __forceinline__ float bf2f(unsigned short u) {
    unsigned int x = ((unsigned int)u) << 16;
    return __builtin_bit_cast(float, x);
}
static __device__ __forceinline__ unsigned short f2bf(float f) {
    unsigned int x = __builtin_bit_cast(unsigned int, f);
    unsigned int r = (x + 0x7fffu + ((x >> 16) & 1u)) >> 16;
    return (unsigned short)r;
}
static __device__ __forceinline__ int clampi(int v, int lo, int hi) {
    return v < lo ? lo : (v > hi ? hi : v);
}

// ---------------- edge binning pass A: partition edges into dst>>8 buckets ----------------
__global__ void __launch_bounds__(256) binA_kernel(const int* __restrict__ src, const int* __restrict__ dst,
                                                   int* __restrict__ gcur, uint2* __restrict__ region) {
    __shared__ uint2 stage[CHUNK];          // 16 KB
    __shared__ int hcnt[PADB], hcnt2[PADB], hoff[PADB], garr[PADB];
    __shared__ int s2[256];
    int tid = threadIdx.x;
    int e0  = blockIdx.x * CHUNK;
    int nedge = N_EDGES - e0; if (nedge > CHUNK) nedge = CHUNK;

    for (int b = tid; b < PADB; b += 256) { hcnt[b] = 0; hcnt2[b] = 0; }
    __syncthreads();

    int es[CHUNK / 256], ed[CHUNK / 256];
    #pragma unroll
    for (int j = 0; j < CHUNK / 256; j++) {
        int e = e0 + j * 256 + tid;
        if (e < N_EDGES) {
            es[j] = clampi(src[e], 0, N_NODES - 1);
            ed[j] = clampi(dst[e], 0, N_NODES - 1);
            atomicAdd(&hcnt[ed[j] >> 8], 1);
        } else { es[j] = -1; ed[j] = 0; }
    }
    __syncthreads();

    int v0 = hcnt[2 * tid], v1 = hcnt[2 * tid + 1];
    s2[tid] = v0 + v1; __syncthreads();
    for (int off = 1; off < 256; off <<= 1) {
        int x = (tid >= off) ? s2[tid - off] : 0;
        __syncthreads();
        s2[tid] += x;
        __syncthreads();
    }
    int excl = s2[tid] - (v0 + v1);
    hoff[2 * tid] = excl; hoff[2 * tid + 1] = excl + v0;
    __syncthreads();

    for (int b = tid; b < NB; b += 256) {
        int c = hcnt[b];
        garr[b] = b * SLACK + ((c > 0) ? atomicAdd(&gcur[b], c) : 0);
    }
    __syncthreads();

    #pragma unroll
    for (int j = 0; j < CHUNK / 256; j++) {
        if (es[j] >= 0) {
            int b = ed[j] >> 8;
            int pos = atomicAdd(&hcnt2[b], 1) + hoff[b];
            stage[pos] = (uint2){(unsigned)es[j], (unsigned)ed[j]};
        }
    }
    __syncthreads();

    for (int i = tid; i < nedge; i += 256) {
        uint2 en = stage[i];
        int b = (int)(en.y >> 8);
        int gpos = garr[b] + (i - hoff[b]);
        if (gpos < (b + 1) * SLACK) region[gpos] = en;
    }
}

// ---------------- scan: global bucket prefix ----------------
__global__ void __launch_bounds__(256) scan_kernel(const int* __restrict__ gcur,
                                                   int* __restrict__ hoffG, int* __restrict__ rowptr) {
    __shared__ int s2[256];
    int tid = threadIdx.x;
    int c0 = gcur[2 * tid];     if (c0 > SLACK) c0 = SLACK;
    int c1 = gcur[2 * tid + 1]; if (c1 > SLACK) c1 = SLACK;
    s2[tid] = c0 + c1; __syncthreads();
    for (int off = 1; off < 256; off <<= 1) {
        int x = (tid >= off) ? s2[tid - off] : 0;
        __syncthreads();
        s2[tid] += x;
        __syncthreads();
    }
    int excl = s2[tid] - (c0 + c1);
    hoffG[2 * tid] = excl; hoffG[2 * tid + 1] = excl + c0;
    if (tid == 255) rowptr[N_NODES] = s2[255];
}

// ---------------- binFinish: per-bucket degree + rowptr + csr scatter ----------------
__global__ void __launch_bounds__(256) binFinish_kernel(const uint2* __restrict__ region, const int* __restrict__ gcur,
                                                        const int* __restrict__ hoffG,
                                                        int* __restrict__ rowptr, int* __restrict__ csr) {
    __shared__ int h[256], sc[256], cur[256];
    int b = blockIdx.x, tid = threadIdx.x;
    h[tid] = 0;
    int base = hoffG[b];
    int size = gcur[b]; if (size > SLACK) size = SLACK;
    int node0 = b * 256;
    __syncthreads();
    for (int j = tid; j < size; j += 256) {
        unsigned loc = region[b * SLACK + j].y - (unsigned)node0;
        if (loc < 256u) atomicAdd(&h[loc], 1);
    }
    __syncthreads();
    int v = h[tid]; sc[tid] = v; __syncthreads();
    for (int off = 1; off < 256; off <<= 1) {
        int x = (tid >= off) ? sc[tid - off] : 0;
        __syncthreads();
        sc[tid] += x;
        __syncthreads();
    }
    int myptr = base + sc[tid] - v;
    int node = node0 + tid;
    if (node < N_NODES) rowptr[node] = myptr;
    cur[tid] = myptr;
    __syncthreads();
    for (int j = tid; j < size; j += 256) {
        uint2 en = region[b * SLACK + j];
        unsigned loc = en.y - (unsigned)node0;
        if (loc < 256u) {
            int p = atomicAdd(&cur[loc], 1);
            if (p >= 0 && p < N_EDGES) csr[p] = (int)en.x;
        }
    }
}

// ---------------- fused prep: cvt + weight fragments + zero rows + gcur/psum clear ----------------
__global__ void __launch_bounds__(256) prep_kernel(const float* __restrict__ x, unsigned short* __restrict__ B2,
                                                   const float* __restrict__ W1rel, const float* __restrict__ W1root,
                                                   const float* __restrict__ W2rel, const float* __restrict__ W2root,
                                                   const float* __restrict__ W3rel, const float* __restrict__ W3root,
                                                   unsigned short* __restrict__ frag,
                                                   unsigned short* __restrict__ z1, unsigned short* __restrict__ z2,
                                                   int* __restrict__ gcur, float* __restrict__ psum) {
    int bid = blockIdx.x, tid = threadIdx.x;
    if (bid < 12500) {                       // cvt: 12500*256*4 == N_NODES*DCH exactly
        size_t i = ((size_t)bid * 256 + tid) * 4;
        float4 f = *reinterpret_cast<const float4*>(x + i);
        uint2 o;
        o.x = ((unsigned)f2bf(f.y) << 16) | (unsigned)f2bf(f.x);
        o.y = ((unsigned)f2bf(f.w) << 16) | (unsigned)f2bf(f.z);
        *reinterpret_cast<uint2*>(B2 + i) = o;
    } else if (bid < 12548) {                // wfrag: 48*256 == 12288 == 3*8*8*64
        int gid = (bid - 12500) * 256 + tid;
        int lane = gid & 63;
        int nt   = (gid >> 6) & 7;
        int kt   = (gid >> 9) & 7;
        int L    = gid >> 12;
        const float* rel  = (L == 0) ? W1rel  : (L == 1) ? W2rel  : W3rel;
        const float* root = (L == 0) ? W1root : (L == 1) ? W2root : W3root;
        int n  = nt * 16 + (lane & 15);
        int k0 = kt * 32 + (lane >> 4) * 8;
        unsigned short o[8];
        #pragma unroll
        for (int j = 0; j < 8; j++) {
            int k = k0 + j;
            float w = (k < 128) ? rel[k * 128 + n] : root[(k - 128) * 128 + n];
            o[j] = f2bf(w);
        }
        uint4 u;
        u.x = (unsigned)o[0] | ((unsigned)o[1] << 16);
        u.y = (unsigned)o[2] | ((unsigned)o[3] << 16);
        u.z = (unsigned)o[4] | ((unsigned)o[5] << 16);
        u.w = (unsigned)o[6] | ((unsigned)o[7] << 16);
        *reinterpret_cast<uint4*>(frag + (size_t)gid * 8) = u;
    } else if (bid == 12548) {               // zero rows + gcur clear
        if (tid < 64)       reinterpret_cast<unsigned*>(z1)[tid] = 0;
        else if (tid < 128) reinterpret_cast<unsigned*>(z2)[tid - 64] = 0;
        gcur[tid] = 0; gcur[tid + 256] = 0;
    } else {                                 // psum clear: 32 blocks * 256 * float4 = 32768 floats
        int i = (bid - 12549) * 1024 + tid * 4;
        *reinterpret_cast<float4*>(psum + i) = (float4){0.f, 0.f, 0.f, 0.f};
    }
}

// ---------------- fused layer: agg (mean gather) + GEMM + bias + relu/pool ----------------
// 256-thread blocks, 4 waves; each wave owns 16 output rows + a private 4 KB LDS slab.
// Agg = flat edge stream, 3-DEEP FIFO-CORRECT pipeline (r4 post-mortem: the 2-deep
// version issued the csr prefetch AFTER the gathers, then read it at the next stage
// start -> vmcnt(0) drain per stage, zero overlap).
// Stage(c), strict issue order:
//   1. issue csr raw load for chunk c+4          (FIRST -> older than gathers)
//   2. select idx from chunk c+2's raw (landed 2 stages ago) + issue its 16 gathers
//   3. accumulate chunk c (its gathers issued 2 stages ago, ~2 stage-bodies + TLP
//      of cover; the wait leaves all newer gathers in flight: counted vmcnt, no drain)
// ~35 loads in flight/wave. Padded lanes gather the L1-resident all-zero row N_NODES.
// Named v0/v1/v2 buffers, fully unrolled: all register indexing compile-time.
// mode: 0 = plain store, 1 = relu store, 2 = pooled (atomicAdd per-graph sums).
__global__ void __launch_bounds__(256, 4) layer_kernel(
    const unsigned short* __restrict__ hin,   // N_NODES+1 rows; row N_NODES is zero
    const int* __restrict__ rowptr, const int* __restrict__ csr,
    const unsigned short* __restrict__ frag, const float* __restrict__ bias,
    unsigned short* __restrict__ hout,
    const int* __restrict__ batch, float* __restrict__ psum, int mode)
{
    __shared__ __attribute__((aligned(16))) unsigned short As[4][16 * DCH];  // 16 KB
    const int wave = threadIdx.x >> 6;
    const int lane = threadIdx.x & 63;
    const int l16  = lane & 15;
    const int quad = lane >> 4;
    const int base = blockIdx.x * 64 + wave * 16;
    if (base >= N_NODES) return;             // no barriers in kernel: early-out safe

    char* Asb = reinterpret_cast<char*>(As[wave]);

    // rowptr[base .. base+16]: one coalesced load; readlane thereafter (SGPR)
    int ridx = base + (lane < 17 ? lane : 16);
    if (ridx > N_NODES) ridx = N_NODES;
    int rp = rowptr[ridx];
    const int R0 = __builtin_amdgcn_readlane(rp, 0);
    const int R1 = __builtin_amdgcn_readlane(rp, 16);

    int ni     = 0;                          // current node (0..15), scalar
    int nstart = R0;
    int nend   = __builtin_amdgcn_readlane(rp, 1);
    float a0 = 0.f, a1 = 0.f;

    // chunk count, padded to multiple of 3 (padded edges gather the zero row)
    int nch = (R1 - R0 + 15) >> 4;
    if (nch < 1) nch = 1;
    const int nch3 = ((nch + 2) / 3) * 3;

    unsigned v0[16], v1[16], v2[16];
    int t0, t1, t2;

    auto issue_gathers = [&](unsigned (&vv)[16], int traw, int eb) {
        int idx = (eb + l16 < R1) ? traw : N_NODES;
        #pragma unroll
        for (int j = 0; j < 16; j++) {
            int s = __builtin_amdgcn_readlane(idx, j);           // SGPR -> saddr gather
            vv[j] = *reinterpret_cast<const unsigned*>(hin + (size_t)s * DCH + lane * 2);
        }
    };
    auto accum = [&](unsigned (&vv)[16], int eb) {
        #pragma unroll
        for (int j = 0; j < 16; j++) {
            int e = eb + j;                                      // uniform
            while (ni < 16 && e == nend) {                       // finalize node ni
                int deg = nend - nstart;
                float inv = 1.0f / (float)(deg > 1 ? deg : 1);
                unsigned o = ((unsigned)f2bf(a1 * inv) << 16) | (unsigned)f2bf(a0 * inv);
                *reinterpret_cast<unsigned*>(Asb + ni * 256 + ((lane * 4) ^ ((ni & 7) << 4))) = o;
                a0 = 0.f; a1 = 0.f;
                ni++;
                nstart = nend;
                nend = __builtin_amdgcn_readlane(rp, ni + 1 < 17 ? ni + 1 : 16);
            }
            a0 += bf2f((unsigned short)(vv[j] & 0xffffu));       // padded edges add 0
            a1 += bf2f((unsigned short)(vv[j] >> 16));
        }
    };

    // prologue: raws for chunks 0,1,2; gathers 0; raw 3 (into freed slot 0); gathers 1
    t0 = csr[R0 + l16];
    t1 = csr[R0 + 16 + l16];
    t2 = csr[R0 + 32 + l16];
    issue_gathers(v0, t0, R0);
    t0 = csr[R0 + 48 + l16];                 // raw chunk 3
    issue_gathers(v1, t1, R0 + 16);

    int e0 = R0;
    for (int c = 0; c < nch3; c += 3) {
        // stage A: raw c+4 -> t1 | gathers c+2 from t2 | accumulate chunk c (v0)
        t1 = csr[e0 + 64 + l16];
        issue_gathers(v2, t2, e0 + 32);
        accum(v0, e0);
        e0 += 16;
        // stage B: raw c+5 -> t2 | gathers c+3 from t0 | accumulate chunk c+1 (v1)
        t2 = csr[e0 + 64 + l16];
        issue_gathers(v0, t0, e0 + 32);
        accum(v1, e0);
        e0 += 16;
        // stage C: raw c+6 -> t0 | gathers c+4 from t1 | accumulate chunk c+2 (v2)
        t0 = csr[e0 + 64 + l16];
        issue_gathers(v1, t1, e0 + 32);
        accum(v2, e0);
        e0 += 16;
    }
    while (ni < 16) {                        // finalize tail (incl. zero-degree nodes)
        int deg = nend - nstart;
        float inv = 1.0f / (float)(deg > 1 ? deg : 1);
        unsigned o = ((unsigned)f2bf(a1 * inv) << 16) | (unsigned)f2bf(a0 * inv);
        *reinterpret_cast<unsigned*>(Asb + ni * 256 + ((lane * 4) ^ ((ni & 7) << 4))) = o;
        a0 = 0.f; a1 = 0.f;
        ni++;
        nstart = nend;
        nend = __builtin_amdgcn_readlane(rp, ni + 1 < 17 ? ni + 1 : 16);
    }
    // wave-private LDS: compiler lgkmcnt covers write->read dep; no barrier.

    // ---------- MFMA: M=16 tile, [agg | root] @ [Wrel; Wroot] ----------
    v4f acc[8];
    #pragma unroll
    for (int nt = 0; nt < 8; nt++) acc[nt] = (v4f){0.f, 0.f, 0.f, 0.f};

    #pragma unroll
    for (int kt = 0; kt < 8; kt++) {
        v8s av;
        if (kt < 4) {
            int co = (kt * 64 + quad * 16) ^ ((l16 & 7) << 4);
            av = *reinterpret_cast<const v8s*>(Asb + l16 * 256 + co);
        } else {
            int ak = (kt - 4) * 32 + quad * 8;
            int row = base + l16; if (row > N_NODES) row = N_NODES;
            av = *reinterpret_cast<const v8s*>(hin + (size_t)row * DCH + ak);
        }
        #pragma unroll
        for (int nt = 0; nt < 8; nt++) {
            v8s b = *reinterpret_cast<const v8s*>(frag + (((size_t)(kt * 8 + nt)) * 64 + lane) * 8);
            acc[nt] = __builtin_amdgcn_mfma_f32_16x16x32_bf16(av, b, acc[nt], 0, 0, 0);
        }
    }

    if (mode != 2) {
        #pragma unroll
        for (int nt = 0; nt < 8; nt++) {
            int n = nt * 16 + l16;
            float bv = bias[n];
            #pragma unroll
            for (int r = 0; r < 4; r++) {
                int row = base + quad * 4 + r;
                if (row < N_NODES) {
                    float v = acc[nt][r] + bv;
                    if (mode == 1) v = fmaxf(v, 0.f);
                    hout[(size_t)row * DCH + n] = f2bf(v);
                }
            }
        }
    } else {
        // pooled epilogue: per-graph sums (mean + matvec applied in final_kernel)
        int last = base + 15;
        bool fast = (last < N_NODES) && (batch[base] == batch[last]);
        if (fast) {
            int g = batch[base];             // all 16 rows same graph (~94% of waves)
            #pragma unroll
            for (int nt = 0; nt < 8; nt++) {
                int n = nt * 16 + l16;
                float s = acc[nt][0] + acc[nt][1] + acc[nt][2] + acc[nt][3] + 4.0f * bias[n];
                s += __shfl_xor(s, 16);      // reduce across quads (rows)
                s += __shfl_xor(s, 32);
                if (quad == 0) atomicAdd(&psum[g * DCH + n], s);
            }
        } else {
            int g[4];
            #pragma unroll
            for (int r = 0; r < 4; r++) {
                int row = base + quad * 4 + r;
                g[r] = (row < N_NODES) ? batch[row] : -1;
            }
            #pragma unroll
            for (int nt = 0; nt < 8; nt++) {
                int n = nt * 16 + l16;
                float bv = bias[n];
                float s = 0.f; int cg = -1;
                #pragma unroll
                for (int r = 0; r < 4; r++) {
                    if (g[r] < 0) continue;
                    if (g[r] != cg) {
                        if (cg >= 0) atomicAdd(&psum[cg * DCH + n], s);
                        s = 0.f; cg = g[r];
                    }
                    s += acc[nt][r] + bv;
                }
                if (cg >= 0) atomicAdd(&psum[cg * DCH + n], s);
            }
        }
    }
}

// ---------------- final: out[g] = (psum[g]/cnt_g) @ Wl + bl ----------------
static __device__ __forceinline__ int lowerb(const int* __restrict__ a, int n, int key) {
    int lo = 0, hi = n;
    while (lo < hi) { int mid = (lo + hi) >> 1; if (a[mid] < key) lo = mid + 1; else hi = mid; }
    return lo;
}

__global__ void __launch_bounds__(64) final_kernel(const float* __restrict__ psum,
                                                   const int* __restrict__ batch,
                                                   const float* __restrict__ Wl, const float* __restrict__ bl,
                                                   float* __restrict__ out) {
    __shared__ float ps[DCH];
    __shared__ int bounds[2];
    int g = blockIdx.x, tid = threadIdx.x;
    if (tid == 0) {
        bounds[0] = lowerb(batch, N_NODES, g);
        bounds[1] = lowerb(batch, N_NODES, g + 1);
    }
    __syncthreads();
    int cnt = bounds[1] - bounds[0];
    float inv = 1.0f / (float)(cnt > 1 ? cnt : 1);
    ps[tid] = psum[g * DCH + tid] * inv;
    ps[tid + 64] = psum[g * DCH + tid + 64] * inv;
    __syncthreads();
    float o = 0.f;
    #pragma unroll 4
    for (int c = 0; c < DCH; c++) o += ps[c] * Wl[c * DOUT + tid];
    out[g * DOUT + tid] = o + bl[tid];
}

extern "C" void kernel_launch(void* const* d_in, const int* in_sizes, int n_in,
                              void* d_out, int out_size, void* d_ws, size_t ws_size,
                              hipStream_t stream) {
    const float* x     = (const float*)d_in[0];
    const int*   edge  = (const int*)d_in[1];
    const int*   src   = edge;
    const int*   dst   = edge + N_EDGES;
    const int*   batch = (const int*)d_in[2];
    const float* W1rel  = (const float*)d_in[3];
    const float* b1     = (const float*)d_in[4];
    const float* W1root = (const float*)d_in[5];
    const float* W2rel  = (const float*)d_in[6];
    const float* b2     = (const float*)d_in[7];
    const float* W2root = (const float*)d_in[8];
    const float* W3rel  = (const float*)d_in[9];
    const float* b3     = (const float*)d_in[10];
    const float* W3root = (const float*)d_in[11];
    const float* Wl     = (const float*)d_in[12];
    const float* bl     = (const float*)d_in[13];
    float* out = (float*)d_out;

    char* ws = (char*)d_ws;
    size_t off = 0;
    auto carve = [&](size_t bytes) -> void* {
        void* p = ws + off;
        off += (bytes + 255) & ~(size_t)255;
        return p;
    };
    int*            rowptr  = (int*)carve((size_t)(N_NODES + 1) * 4);
    int*            csr     = (int*)carve((size_t)(N_EDGES + 160) * 4);  // +160: 3-deep prefetch slack
    int*            gcur    = (int*)carve((size_t)PADB * 4 + (size_t)N_GRAPHS * DCH * 4); // gcur + psum
    float*          psum    = (float*)(gcur + PADB);
    int*            hoffG   = (int*)carve((size_t)PADB * 4);
    unsigned short* frag    = (unsigned short*)carve((size_t)3 * 8 * 8 * 64 * 8 * 2);
    unsigned short* B1      = (unsigned short*)carve((size_t)(N_NODES + 1) * DCH * 2);   // +1 zero row
    unsigned short* B2      = (unsigned short*)carve((size_t)(N_NODES + 1) * DCH * 2);   // +1 zero row
    uint2*          region  = (uint2*)B1;   // 391*4608*8 = 14.4 MB <= 25.6 MB (zero row beyond region)

    // prep first: cvt + frags + zero rows + gcur/psum clear (replaces hipMemsetAsync)
    prep_kernel<<<12581, 256, 0, stream>>>(x, B2, W1rel, W1root, W2rel, W2root, W3rel, W3root,
                                           frag, B1 + (size_t)N_NODES * DCH, B2 + (size_t)N_NODES * DCH,
                                           gcur, psum);

    // CSR build: binA -> scan -> binFinish
    binA_kernel<<<(N_EDGES + CHUNK - 1) / CHUNK, 256, 0, stream>>>(src, dst, gcur, region);
    scan_kernel<<<1, 256, 0, stream>>>(gcur, hoffG, rowptr);
    binFinish_kernel<<<NB, 256, 0, stream>>>(region, gcur, hoffG, rowptr, csr);

    const int layerGrid = (N_NODES + 63) / 64;   // 1563 blocks x 4 waves x 16 rows

    // fused layers; ping-pong B2 -> B1 -> B2; layer 3 pools directly into psum
    layer_kernel<<<layerGrid, 256, 0, stream>>>(B2, rowptr, csr, frag,         b1, B1, batch, psum, 1);
    layer_kernel<<<layerGrid, 256, 0, stream>>>(B1, rowptr, csr, frag + 32768, b2, B2, batch, psum, 1);
    layer_kernel<<<layerGrid, 256, 0, stream>>>(B2, rowptr, csr, frag + 65536, b3, B1, batch, psum, 2);

    final_kernel<<<N_GRAPHS, 64, 0, stream>>>(psum, batch, Wl, bl, out);
}